// Round 6
// baseline (264.340 us; speedup 1.0000x reference)
//
#include <hip/hip_runtime.h>
#include <cstdint>
#include <cstddef>

// Problem constants
#define B_ 8
#define C_ 512
#define L_ 4096
#define M_ 2048   // L/2 (pooled keys)
#define CK_ 64    // C/8
#define CV_ 256   // C/2

typedef _Float16 f16;
typedef _Float16 f16x8 __attribute__((ext_vector_type(8)));
typedef _Float16 f16x4 __attribute__((ext_vector_type(4)));
typedef float f32x4 __attribute__((ext_vector_type(4)));
typedef float f32x16 __attribute__((ext_vector_type(16)));
typedef unsigned int u32x4 __attribute__((ext_vector_type(4)));

#define MFMA16(A, Bv, Cv) __builtin_amdgcn_mfma_f32_16x16x32_f16(A, Bv, Cv, 0, 0, 0)
#define MFMA32(A, Bv, Cv) __builtin_amdgcn_mfma_f32_32x32x16_f16(A, Bv, Cv, 0, 0, 0)

static __device__ __forceinline__ uint32_t pkrtz(float a, float b) {
    return __builtin_bit_cast(uint32_t, __builtin_amdgcn_cvt_pkrtz(a, b));
}

// ---------------------------------------------------------------------------
// Kernel X: x fp32 -> x2[b][c>>3][l][8] f16 (fragment-native).
//   8 coalesced dword streams in, one 16B lane store out.
// ---------------------------------------------------------------------------
__global__ __launch_bounds__(256) void xcvt(const float* __restrict__ x,
                                            f16* __restrict__ x2) {
    const int b  = blockIdx.z;
    const int co = blockIdx.y;          // c-octet
    const int l  = blockIdx.x * 256 + threadIdx.x;
    const float* xp = x + ((size_t)b * C_ + co * 8) * L_ + l;
    float v[8];
#pragma unroll
    for (int i = 0; i < 8; ++i) v[i] = xp[(size_t)i * L_];
    u32x4 p = {pkrtz(v[0], v[1]), pkrtz(v[2], v[3]),
               pkrtz(v[4], v[5]), pkrtz(v[6], v[7])};
    *reinterpret_cast<u32x4*>(x2 + ((size_t)(b * 64 + co) * L_ + l) * 8) = p;
}

// ---------------------------------------------------------------------------
// Kernel W: fp32 -> f16 convert (W matrices)
// ---------------------------------------------------------------------------
__global__ __launch_bounds__(256) void cvt_kernel(const float* __restrict__ in,
                                                  f16* __restrict__ out, int n) {
    int i = blockIdx.x * 256 + threadIdx.x;
    if (i < n) out[i] = (f16)in[i];
}

// ---------------------------------------------------------------------------
// Fused projection kernel (MFMA f16, fp32 accum), fragment-native operands.
//   All 384 output channels (theta 64 | phi 64 | g 256) for a 32-l tile.
//   A = Wall rows (f16, 16B/lane), B = x2 frags (16B/lane coalesced).
//   phi/g maxpool2 over l via shfl_xor(1) on D cols (col = lane).
//   Outputs: theta2[b][ck>>3][l][8]  phi2[b][ck>>3][m][8]  g2[b][m>>3][v][8]
// ---------------------------------------------------------------------------
__global__ __launch_bounds__(256) void fused_proj(const f16* __restrict__ Wall,
                                                  const f16* __restrict__ x2,
                                                  f16* __restrict__ theta2,
                                                  f16* __restrict__ phi2,
                                                  f16* __restrict__ g2) {
    const int b    = blockIdx.y;
    const int l0   = blockIdx.x * 32;
    const int w    = threadIdx.x >> 6;   // warp: och range [w*96, w*96+96)
    const int lane = threadIdx.x & 63;
    const int lq   = lane & 15;
    const int g    = lane >> 4;
    const int wb   = w * 96;

    f32x4 acc[6][2] = {};
    const f16* xb = x2 + (size_t)b * 64 * L_ * 8;

    for (int ks = 0; ks < 16; ++ks) {
        const int c0 = ks * 32;
        f16x8 Bf[2];
#pragma unroll
        for (int lt = 0; lt < 2; ++lt)
            Bf[lt] = *reinterpret_cast<const f16x8*>(
                xb + ((size_t)(ks * 4 + g) * L_ + l0 + lt * 16 + lq) * 8);
#pragma unroll
        for (int t = 0; t < 6; ++t) {
            f16x8 Af = *reinterpret_cast<const f16x8*>(
                Wall + (size_t)(wb + t * 16 + lq) * C_ + c0 + 8 * g);
            acc[t][0] = MFMA16(Af, Bf[0], acc[t][0]);
            acc[t][1] = MFMA16(Af, Bf[1], acc[t][1]);
        }
    }

    // Epilogue. D layout (MFMA16): row = 4g + r (och), col = lq (l).
#pragma unroll
    for (int t = 0; t < 6; ++t) {
        const int och0 = wb + t * 16;
#pragma unroll
        for (int lt = 0; lt < 2; ++lt) {
            const int l = l0 + lt * 16 + lq;
            if (och0 < 64) {
#pragma unroll
                for (int r = 0; r < 4; ++r) {
                    const int och = och0 + 4 * g + r;
                    theta2[(((size_t)b * 8 + (och >> 3)) * L_ + l) * 8 + (och & 7)] =
                        (f16)acc[t][lt][r];
                }
            } else {
#pragma unroll
                for (int r = 0; r < 4; ++r) {
                    const float pv = fmaxf(acc[t][lt][r], __shfl_xor(acc[t][lt][r], 1));
                    if (!(lane & 1)) {
                        const int m = l >> 1;
                        if (och0 < 128) {
                            const int kc = och0 - 64 + 4 * g + r;
                            phi2[(((size_t)b * 8 + (kc >> 3)) * M_ + m) * 8 + (kc & 7)] =
                                (f16)pv;
                        } else {
                            const int vc = och0 - 128 + 4 * g + r;
                            g2[(((size_t)b * 256 + (m >> 3)) * CV_ + vc) * 8 + (m & 7)] =
                                (f16)pv;
                        }
                    }
                }
            }
        }
    }
}

// ---------------------------------------------------------------------------
// Kernel B: flash attention, zero LDS / zero barriers, K/V double-buffered.
//   Structure verified in rounds 4/5; this round adds next-step register
//   prefetch (T14) + s_setprio around MFMA clusters (T5).
// ---------------------------------------------------------------------------
__global__ __launch_bounds__(256) void attn_flash(const f16* __restrict__ theta2,
                                                  const f16* __restrict__ phi2,
                                                  const f16* __restrict__ g2,
                                                  f16* __restrict__ o_inT) {
    const int bid = blockIdx.x;
    const int swz = (bid & 7) * 64 + (bid >> 3);  // XCD-major: batch = bid&7
    const int b   = swz >> 6;
    const int qt  = swz & 63;
    const int w   = threadIdx.x >> 6;
    const int qg  = w >> 1;
    const int vh  = w & 1;
    const int q0  = qt * 64 + qg * 32;     // 32 queries for this warp
    const int vb  = vh * 128;              // 128 v-rows for this warp
    const int lane = threadIdx.x & 63;
    const int lq   = lane & 31;
    const int hi   = lane >> 5;

    const f16* qbase = theta2 + (size_t)b * 8 * L_ * 8;
    f16x8 Qf[4];
#pragma unroll
    for (int f = 0; f < 4; ++f)
        Qf[f] = *reinterpret_cast<const f16x8*>(
            qbase + ((size_t)(2 * f + hi) * L_ + q0 + lq) * 8);

    f32x16 acc[4] = {};
    float m_run = -3.0e38f;
    float l_run = 0.f;

    const f16* kbase = phi2 + (size_t)b * 8 * M_ * 8;
    const f16* vbase = g2 + (size_t)b * 256 * CV_ * 8;

#define LOADK(dst, mm)                                                        \
    _Pragma("unroll")                                                         \
    for (int f = 0; f < 4; ++f)                                               \
        dst[f] = *reinterpret_cast<const f16x8*>(                             \
            kbase + ((size_t)(2 * f + hi) * M_ + (mm) + lq) * 8);
#define LOADV(dst, mm)                                                        \
    _Pragma("unroll")                                                         \
    for (int ch = 0; ch < 2; ++ch)                                            \
        _Pragma("unroll")                                                     \
        for (int vt = 0; vt < 4; ++vt)                                        \
            dst[ch][vt] = *reinterpret_cast<const f16x8*>(                    \
                vbase + ((size_t)(((mm) >> 3) + 2 * ch + hi) * CV_ +          \
                         vb + vt * 32 + lq) * 8);

    f16x8 Kc[4], Vc[2][4];
    LOADK(Kc, 0);
    LOADV(Vc, 0);

    for (int m0 = 0; m0 < M_; m0 += 32) {
        // ---- prefetch next step (wraps to 0 on last iter; harmless) ----
        const int mn = (m0 + 32) & (M_ - 1);
        f16x8 Kn[4], Vn[2][4];
        LOADK(Kn, mn);
        LOADV(Vn, mn);

        // ---- QK^T: S^T[m][q], col = q = lq ----
        f32x16 S = {};
        __builtin_amdgcn_s_setprio(1);
#pragma unroll
        for (int f = 0; f < 4; ++f) S = MFMA32(Kc[f], Qf[f], S);
        __builtin_amdgcn_s_setprio(0);

        float s[16];
#pragma unroll
        for (int r = 0; r < 16; ++r) s[r] = S[r];

        // ---- online softmax (per-lane; q is lane-local) ----
        float tm = s[0];
#pragma unroll
        for (int r = 1; r < 16; ++r) tm = fmaxf(tm, s[r]);
        tm = fmaxf(tm, __shfl_xor(tm, 32));
        if (tm > m_run + 8.f) {  // defer-max
            float sc = __expf(m_run - tm);
#pragma unroll
            for (int vt = 0; vt < 4; ++vt)
#pragma unroll
                for (int r = 0; r < 16; ++r) acc[vt][r] *= sc;
            l_run *= sc;
            m_run = tm;
        }
        float ls = 0.f;
#pragma unroll
        for (int r = 0; r < 16; ++r) {
            s[r] = __expf(s[r] - m_run);
            ls += s[r];
        }
        l_run += ls + __shfl_xor(ls, 32);

        // ---- P -> f16 B-fragments (cvt_pkrtz + permlane32_swap, T12) ----
        uint32_t pk[8];
#pragma unroll
        for (int i = 0; i < 8; ++i) pk[i] = pkrtz(s[2 * i], s[2 * i + 1]);
        asm volatile("v_permlane32_swap_b32 %0, %1" : "+v"(pk[0]), "+v"(pk[2]));
        asm volatile("v_permlane32_swap_b32 %0, %1" : "+v"(pk[1]), "+v"(pk[3]));
        asm volatile("v_permlane32_swap_b32 %0, %1" : "+v"(pk[4]), "+v"(pk[6]));
        asm volatile("v_permlane32_swap_b32 %0, %1" : "+v"(pk[5]), "+v"(pk[7]));
        u32x4 fr0 = {pk[0], pk[1], pk[2], pk[3]};
        u32x4 fr1 = {pk[4], pk[5], pk[6], pk[7]};
        f16x8 P0 = __builtin_bit_cast(f16x8, fr0);
        f16x8 P1 = __builtin_bit_cast(f16x8, fr1);

        // ---- PV ----
        __builtin_amdgcn_s_setprio(1);
#pragma unroll
        for (int vt = 0; vt < 4; ++vt) acc[vt] = MFMA32(Vc[0][vt], P0, acc[vt]);
#pragma unroll
        for (int vt = 0; vt < 4; ++vt) acc[vt] = MFMA32(Vc[1][vt], P1, acc[vt]);
        __builtin_amdgcn_s_setprio(0);

        // ---- rotate prefetch -> current ----
#pragma unroll
        for (int f = 0; f < 4; ++f) Kc[f] = Kn[f];
#pragma unroll
        for (int ch = 0; ch < 2; ++ch)
#pragma unroll
            for (int vt = 0; vt < 4; ++vt) Vc[ch][vt] = Vn[ch][vt];
    }
#undef LOADK
#undef LOADV

    // ---- epilogue: normalize, store o_inT[b][q][v] ----
    const float inv = 1.f / l_run;
    f16* op = o_inT + ((size_t)b * L_ + q0 + lq) * CV_ + vb + 4 * hi;
#pragma unroll
    for (int vt = 0; vt < 4; ++vt)
#pragma unroll
        for (int rq = 0; rq < 4; ++rq) {
            f16x4 o;
#pragma unroll
            for (int j = 0; j < 4; ++j) o[j] = (f16)(acc[vt][4 * rq + j] * inv);
            *reinterpret_cast<f16x4*>(op + vt * 32 + 8 * rq) = o;
        }
}

// ---------------------------------------------------------------------------
// Kernel C: MFMA output projection + residual.
// ---------------------------------------------------------------------------
__global__ __launch_bounds__(256) void out_mfma(const f16* __restrict__ Wo_h,
                                                const f16* __restrict__ o_inT,
                                                const float* __restrict__ x,
                                                const float* __restrict__ gamma_p,
                                                float* __restrict__ out) {
    const int b    = blockIdx.z;
    const int l0   = blockIdx.x * 64;
    const int wid  = threadIdx.x >> 6;
    const int oc0  = blockIdx.y * 64 + wid * 16;
    const int lane = threadIdx.x & 63;
    const int lq   = lane & 15;
    const int g    = lane >> 4;

    f32x4 acc[4] = {{0.f, 0.f, 0.f, 0.f}, {0.f, 0.f, 0.f, 0.f},
                    {0.f, 0.f, 0.f, 0.f}, {0.f, 0.f, 0.f, 0.f}};
    const f16* ap = Wo_h + (size_t)(oc0 + lq) * CV_;
#pragma unroll
    for (int ks = 0; ks < 8; ++ks) {
        f16x8 A = *reinterpret_cast<const f16x8*>(ap + ks * 32 + 8 * g);
#pragma unroll
        for (int lt = 0; lt < 4; ++lt) {
            const f16* bp = o_inT + ((size_t)b * L_ + l0 + lt * 16 + lq) * CV_ + ks * 32 + 8 * g;
            acc[lt] = MFMA16(A, *reinterpret_cast<const f16x8*>(bp), acc[lt]);
        }
    }
    const float gamma = *gamma_p;
#pragma unroll
    for (int lt = 0; lt < 4; ++lt)
#pragma unroll
        for (int r = 0; r < 4; ++r) {
            const size_t o = ((size_t)b * C_ + oc0 + 4 * g + r) * L_ + l0 + lt * 16 + lq;
            out[o] = fmaf(gamma, acc[lt][r], x[o]);
        }
}

// ---------------------------------------------------------------------------
extern "C" void kernel_launch(void* const* d_in, const int* in_sizes, int n_in,
                              void* d_out, int out_size, void* d_ws, size_t ws_size,
                              hipStream_t stream) {
    const float* x       = (const float*)d_in[0];
    const float* W_theta = (const float*)d_in[1];
    const float* W_phi   = (const float*)d_in[2];
    const float* W_g     = (const float*)d_in[3];
    const float* W_o     = (const float*)d_in[4];
    const float* gamma   = (const float*)d_in[5];
    float* out = (float*)d_out;

    // workspace carve (f16): x2 | theta2 | phi2 | g2 | o_inT | Wo_h | Wall
    // 32 + 4 + 2 + 8 + 16 + 0.25 + 0.375 = 62.6 MiB
    f16* x2     = (f16*)d_ws;                          // [B][64][L][8]
    f16* theta2 = x2 + (size_t)B_ * C_ * L_;           // [B][8][L][8]
    f16* phi2   = theta2 + (size_t)B_ * 8 * L_ * 8;    // [B][8][M][8]
    f16* g2     = phi2 + (size_t)B_ * 8 * M_ * 8;      // [B][256][CV][8]
    f16* o_inT  = g2 + (size_t)B_ * 256 * CV_ * 8;     // [B][L][CV]
    f16* Wo_h   = o_inT + (size_t)B_ * L_ * CV_;       // [C][CV]
    f16* Wall   = Wo_h + (size_t)C_ * CV_;             // [384][C]

    cvt_kernel<<<dim3((C_ * CV_) / 256), 256, 0, stream>>>(W_o, Wo_h, C_ * CV_);
    cvt_kernel<<<dim3((CK_ * C_) / 256), 256, 0, stream>>>(W_theta, Wall, CK_ * C_);
    cvt_kernel<<<dim3((CK_ * C_) / 256), 256, 0, stream>>>(W_phi, Wall + CK_ * C_, CK_ * C_);
    cvt_kernel<<<dim3((CV_ * C_) / 256), 256, 0, stream>>>(W_g, Wall + 2 * CK_ * C_, CV_ * C_);
    xcvt<<<dim3(L_ / 256, C_ / 8, B_), 256, 0, stream>>>(x, x2);
    fused_proj<<<dim3(L_ / 32, B_), 256, 0, stream>>>(Wall, x2, theta2, phi2, g2);
    attn_flash<<<dim3(512), 256, 0, stream>>>(theta2, phi2, g2, o_inT);
    out_mfma<<<dim3(L_ / 64, C_ / 64, B_), 256, 0, stream>>>(Wo_h, o_inT, x, gamma, out);
}

// Round 7
// 262.146 us; speedup vs baseline: 1.0084x; 1.0084x over previous
//
#include <hip/hip_runtime.h>
#include <cstdint>
#include <cstddef>

// Problem constants
#define B_ 8
#define C_ 512
#define L_ 4096
#define M_ 2048   // L/2 (pooled keys)
#define CK_ 64    // C/8
#define CV_ 256   // C/2

typedef _Float16 f16;
typedef _Float16 f16x8 __attribute__((ext_vector_type(8)));
typedef _Float16 f16x4 __attribute__((ext_vector_type(4)));
typedef float f32x4 __attribute__((ext_vector_type(4)));
typedef float f32x16 __attribute__((ext_vector_type(16)));
typedef unsigned int u32x4 __attribute__((ext_vector_type(4)));

#define MFMA16(A, Bv, Cv) __builtin_amdgcn_mfma_f32_16x16x32_f16(A, Bv, Cv, 0, 0, 0)
#define MFMA32(A, Bv, Cv) __builtin_amdgcn_mfma_f32_32x32x16_f16(A, Bv, Cv, 0, 0, 0)

#define LOG2E 1.44269504f

static __device__ __forceinline__ uint32_t pkrtz(float a, float b) {
    return __builtin_bit_cast(uint32_t, __builtin_amdgcn_cvt_pkrtz(a, b));
}

// ---------------------------------------------------------------------------
// Kernel X: x fp32 -> x2[b][c>>3][l][8] f16 (fragment-native).
// ---------------------------------------------------------------------------
__global__ __launch_bounds__(256) void xcvt(const float* __restrict__ x,
                                            f16* __restrict__ x2) {
    const int b  = blockIdx.z;
    const int co = blockIdx.y;          // c-octet
    const int l  = blockIdx.x * 256 + threadIdx.x;
    const float* xp = x + ((size_t)b * C_ + co * 8) * L_ + l;
    float v[8];
#pragma unroll
    for (int i = 0; i < 8; ++i) v[i] = xp[(size_t)i * L_];
    u32x4 p = {pkrtz(v[0], v[1]), pkrtz(v[2], v[3]),
               pkrtz(v[4], v[5]), pkrtz(v[6], v[7])};
    *reinterpret_cast<u32x4*>(x2 + ((size_t)(b * 64 + co) * L_ + l) * 8) = p;
}

// ---------------------------------------------------------------------------
// Kernel W: fp32 -> f16 convert (W matrices)
// ---------------------------------------------------------------------------
__global__ __launch_bounds__(256) void cvt_kernel(const float* __restrict__ in,
                                                  f16* __restrict__ out, int n) {
    int i = blockIdx.x * 256 + threadIdx.x;
    if (i < n) out[i] = (f16)in[i];
}

// ---------------------------------------------------------------------------
// Fused projection kernel (MFMA f16, fp32 accum), fragment-native operands.
//   theta is written pre-scaled by log2(e) so attn softmax runs in exp2
//   domain (saves 16 v_mul per m-step in the attn hot loop).
// ---------------------------------------------------------------------------
__global__ __launch_bounds__(256) void fused_proj(const f16* __restrict__ Wall,
                                                  const f16* __restrict__ x2,
                                                  f16* __restrict__ theta2,
                                                  f16* __restrict__ phi2,
                                                  f16* __restrict__ g2) {
    const int b    = blockIdx.y;
    const int l0   = blockIdx.x * 32;
    const int w    = threadIdx.x >> 6;   // warp: och range [w*96, w*96+96)
    const int lane = threadIdx.x & 63;
    const int lq   = lane & 15;
    const int g    = lane >> 4;
    const int wb   = w * 96;

    f32x4 acc[6][2] = {};
    const f16* xb = x2 + (size_t)b * 64 * L_ * 8;

    for (int ks = 0; ks < 16; ++ks) {
        const int c0 = ks * 32;
        f16x8 Bf[2];
#pragma unroll
        for (int lt = 0; lt < 2; ++lt)
            Bf[lt] = *reinterpret_cast<const f16x8*>(
                xb + ((size_t)(ks * 4 + g) * L_ + l0 + lt * 16 + lq) * 8);
#pragma unroll
        for (int t = 0; t < 6; ++t) {
            f16x8 Af = *reinterpret_cast<const f16x8*>(
                Wall + (size_t)(wb + t * 16 + lq) * C_ + c0 + 8 * g);
            acc[t][0] = MFMA16(Af, Bf[0], acc[t][0]);
            acc[t][1] = MFMA16(Af, Bf[1], acc[t][1]);
        }
    }

    // Epilogue. D layout (MFMA16): row = 4g + r (och), col = lq (l).
#pragma unroll
    for (int t = 0; t < 6; ++t) {
        const int och0 = wb + t * 16;
#pragma unroll
        for (int lt = 0; lt < 2; ++lt) {
            const int l = l0 + lt * 16 + lq;
            if (och0 < 64) {
#pragma unroll
                for (int r = 0; r < 4; ++r) {
                    const int och = och0 + 4 * g + r;
                    theta2[(((size_t)b * 8 + (och >> 3)) * L_ + l) * 8 + (och & 7)] =
                        (f16)(acc[t][lt][r] * LOG2E);
                }
            } else {
#pragma unroll
                for (int r = 0; r < 4; ++r) {
                    const float pv = fmaxf(acc[t][lt][r], __shfl_xor(acc[t][lt][r], 1));
                    if (!(lane & 1)) {
                        const int m = l >> 1;
                        if (och0 < 128) {
                            const int kc = och0 - 64 + 4 * g + r;
                            phi2[(((size_t)b * 8 + (kc >> 3)) * M_ + m) * 8 + (kc & 7)] =
                                (f16)pv;
                        } else {
                            const int vc = och0 - 128 + 4 * g + r;
                            g2[(((size_t)b * 256 + (m >> 3)) * CV_ + vc) * 8 + (m & 7)] =
                                (f16)pv;
                        }
                    }
                }
            }
        }
    }
}

// ---------------------------------------------------------------------------
// Kernel B: flash attention, zero LDS / zero barriers, v-split 4.
//   Block = 256 thr = 4 warps; each warp: same 32 queries, own 64-v quarter.
//   1024 blocks -> 4096 waves = 4 waves/SIMD (latency hiding via TLP, not
//   manual prefetch — round 6 showed the register-double-buffer regresses).
//   Softmax in exp2 domain (theta pre-scaled by log2e).
// ---------------------------------------------------------------------------
__global__ __launch_bounds__(256, 4) void attn_flash(const f16* __restrict__ theta2,
                                                     const f16* __restrict__ phi2,
                                                     const f16* __restrict__ g2,
                                                     f16* __restrict__ o_inT) {
    const int bid = blockIdx.x;
    const int b   = bid & 7;            // XCD-major: one batch per XCD
    const int qt  = bid >> 3;           // 128 q-tiles per batch
    const int q0  = qt * 32;
    const int vq  = threadIdx.x >> 6;
    const int vb  = vq * 64;            // 64 v-rows for this warp
    const int lane = threadIdx.x & 63;
    const int lq   = lane & 31;
    const int hi   = lane >> 5;

    const f16* qbase = theta2 + (size_t)b * 8 * L_ * 8;
    f16x8 Qf[4];
#pragma unroll
    for (int f = 0; f < 4; ++f)
        Qf[f] = *reinterpret_cast<const f16x8*>(
            qbase + ((size_t)(2 * f + hi) * L_ + q0 + lq) * 8);

    f32x16 acc[2] = {};
    float m_run = -3.0e38f;
    float l_run = 0.f;

    const f16* kbase = phi2 + (size_t)b * 8 * M_ * 8;
    const f16* vbase = g2 + (size_t)b * 256 * CV_ * 8;

    for (int m0 = 0; m0 < M_; m0 += 32) {
        // ---- loads for this step (all coalesced; K identical across warps) ----
        f16x8 Kf[4];
#pragma unroll
        for (int f = 0; f < 4; ++f)
            Kf[f] = *reinterpret_cast<const f16x8*>(
                kbase + ((size_t)(2 * f + hi) * M_ + m0 + lq) * 8);
        f16x8 Vf[2][2];
#pragma unroll
        for (int ch = 0; ch < 2; ++ch)
#pragma unroll
            for (int vt = 0; vt < 2; ++vt)
                Vf[ch][vt] = *reinterpret_cast<const f16x8*>(
                    vbase + ((size_t)((m0 >> 3) + 2 * ch + hi) * CV_ +
                             vb + vt * 32 + lq) * 8);

        // ---- QK^T (scores already in log2 units): S^T[m][q], col = q ----
        f32x16 S = {};
        __builtin_amdgcn_s_setprio(1);
#pragma unroll
        for (int f = 0; f < 4; ++f) S = MFMA32(Kf[f], Qf[f], S);
        __builtin_amdgcn_s_setprio(0);

        // ---- online softmax, exp2 domain (per-lane; q is lane-local) ----
        float tm = S[0];
#pragma unroll
        for (int r = 1; r < 16; ++r) tm = fmaxf(tm, S[r]);
        tm = fmaxf(tm, __shfl_xor(tm, 32));
        if (tm > m_run + 11.5f) {  // defer-max (11.5 log2 units ~= 8 nats)
            float sc = __builtin_amdgcn_exp2f(m_run - tm);
#pragma unroll
            for (int vt = 0; vt < 2; ++vt)
#pragma unroll
                for (int r = 0; r < 16; ++r) acc[vt][r] *= sc;
            l_run *= sc;
            m_run = tm;
        }
        float s[16];
        float ls = 0.f;
#pragma unroll
        for (int r = 0; r < 16; ++r) {
            s[r] = __builtin_amdgcn_exp2f(S[r] - m_run);
            ls += s[r];
        }
        l_run += ls + __shfl_xor(ls, 32);

        // ---- P -> f16 B-fragments (cvt_pkrtz + permlane32_swap, T12) ----
        uint32_t pk[8];
#pragma unroll
        for (int i = 0; i < 8; ++i) pk[i] = pkrtz(s[2 * i], s[2 * i + 1]);
        asm volatile("v_permlane32_swap_b32 %0, %1" : "+v"(pk[0]), "+v"(pk[2]));
        asm volatile("v_permlane32_swap_b32 %0, %1" : "+v"(pk[1]), "+v"(pk[3]));
        asm volatile("v_permlane32_swap_b32 %0, %1" : "+v"(pk[4]), "+v"(pk[6]));
        asm volatile("v_permlane32_swap_b32 %0, %1" : "+v"(pk[5]), "+v"(pk[7]));
        u32x4 fr0 = {pk[0], pk[1], pk[2], pk[3]};
        u32x4 fr1 = {pk[4], pk[5], pk[6], pk[7]};
        f16x8 P0 = __builtin_bit_cast(f16x8, fr0);
        f16x8 P1 = __builtin_bit_cast(f16x8, fr1);

        // ---- PV ----
        __builtin_amdgcn_s_setprio(1);
#pragma unroll
        for (int vt = 0; vt < 2; ++vt) acc[vt] = MFMA32(Vf[0][vt], P0, acc[vt]);
#pragma unroll
        for (int vt = 0; vt < 2; ++vt) acc[vt] = MFMA32(Vf[1][vt], P1, acc[vt]);
        __builtin_amdgcn_s_setprio(0);
    }

    // ---- epilogue: normalize, store o_inT[b][q][v] ----
    const float inv = 1.f / l_run;
    f16* op = o_inT + ((size_t)b * L_ + q0 + lq) * CV_ + vb + 4 * hi;
#pragma unroll
    for (int vt = 0; vt < 2; ++vt)
#pragma unroll
        for (int rq = 0; rq < 4; ++rq) {
            f16x4 o;
#pragma unroll
            for (int j = 0; j < 4; ++j) o[j] = (f16)(acc[vt][4 * rq + j] * inv);
            *reinterpret_cast<f16x4*>(op + vt * 32 + 8 * rq) = o;
        }
}

// ---------------------------------------------------------------------------
// Kernel C: MFMA output projection + residual.
// ---------------------------------------------------------------------------
__global__ __launch_bounds__(256) void out_mfma(const f16* __restrict__ Wo_h,
                                                const f16* __restrict__ o_inT,
                                                const float* __restrict__ x,
                                                const float* __restrict__ gamma_p,
                                                float* __restrict__ out) {
    const int b    = blockIdx.z;
    const int l0   = blockIdx.x * 64;
    const int wid  = threadIdx.x >> 6;
    const int oc0  = blockIdx.y * 64 + wid * 16;
    const int lane = threadIdx.x & 63;
    const int lq   = lane & 15;
    const int g    = lane >> 4;

    f32x4 acc[4] = {{0.f, 0.f, 0.f, 0.f}, {0.f, 0.f, 0.f, 0.f},
                    {0.f, 0.f, 0.f, 0.f}, {0.f, 0.f, 0.f, 0.f}};
    const f16* ap = Wo_h + (size_t)(oc0 + lq) * CV_;
#pragma unroll
    for (int ks = 0; ks < 8; ++ks) {
        f16x8 A = *reinterpret_cast<const f16x8*>(ap + ks * 32 + 8 * g);
#pragma unroll
        for (int lt = 0; lt < 4; ++lt) {
            const f16* bp = o_inT + ((size_t)b * L_ + l0 + lt * 16 + lq) * CV_ + ks * 32 + 8 * g;
            acc[lt] = MFMA16(A, *reinterpret_cast<const f16x8*>(bp), acc[lt]);
        }
    }
    const float gamma = *gamma_p;
#pragma unroll
    for (int lt = 0; lt < 4; ++lt)
#pragma unroll
        for (int r = 0; r < 4; ++r) {
            const size_t o = ((size_t)b * C_ + oc0 + 4 * g + r) * L_ + l0 + lt * 16 + lq;
            out[o] = fmaf(gamma, acc[lt][r], x[o]);
        }
}

// ---------------------------------------------------------------------------
extern "C" void kernel_launch(void* const* d_in, const int* in_sizes, int n_in,
                              void* d_out, int out_size, void* d_ws, size_t ws_size,
                              hipStream_t stream) {
    const float* x       = (const float*)d_in[0];
    const float* W_theta = (const float*)d_in[1];
    const float* W_phi   = (const float*)d_in[2];
    const float* W_g     = (const float*)d_in[3];
    const float* W_o     = (const float*)d_in[4];
    const float* gamma   = (const float*)d_in[5];
    float* out = (float*)d_out;

    // workspace carve (f16): x2 | theta2 | phi2 | g2 | o_inT | Wo_h | Wall
    f16* x2     = (f16*)d_ws;                          // [B][64][L][8]
    f16* theta2 = x2 + (size_t)B_ * C_ * L_;           // [B][8][L][8]
    f16* phi2   = theta2 + (size_t)B_ * 8 * L_ * 8;    // [B][8][M][8]
    f16* g2     = phi2 + (size_t)B_ * 8 * M_ * 8;      // [B][256][CV][8]
    f16* o_inT  = g2 + (size_t)B_ * 256 * CV_ * 8;     // [B][L][CV]
    f16* Wo_h   = o_inT + (size_t)B_ * L_ * CV_;       // [C][CV]
    f16* Wall   = Wo_h + (size_t)C_ * CV_;             // [384][C]

    cvt_kernel<<<dim3((C_ * CV_) / 256), 256, 0, stream>>>(W_o, Wo_h, C_ * CV_);
    cvt_kernel<<<dim3((CK_ * C_) / 256), 256, 0, stream>>>(W_theta, Wall, CK_ * C_);
    cvt_kernel<<<dim3((CK_ * C_) / 256), 256, 0, stream>>>(W_phi, Wall + CK_ * C_, CK_ * C_);
    cvt_kernel<<<dim3((CV_ * C_) / 256), 256, 0, stream>>>(W_g, Wall + 2 * CK_ * C_, CV_ * C_);
    xcvt<<<dim3(L_ / 256, C_ / 8, B_), 256, 0, stream>>>(x, x2);
    fused_proj<<<dim3(L_ / 32, B_), 256, 0, stream>>>(Wall, x2, theta2, phi2, g2);
    attn_flash<<<dim3(1024), 256, 0, stream>>>(theta2, phi2, g2, o_inT);
    out_mfma<<<dim3(L_ / 64, C_ / 64, B_), 256, 0, stream>>>(Wo_h, o_inT, x, gamma, out);
}

// Round 8
// 242.115 us; speedup vs baseline: 1.0918x; 1.0827x over previous
//
#include <hip/hip_runtime.h>
#include <cstdint>
#include <cstddef>

// Problem constants
#define B_ 8
#define C_ 512
#define L_ 4096
#define M_ 2048   // L/2 (pooled keys)
#define CK_ 64    // C/8
#define CV_ 256   // C/2

typedef _Float16 f16;
typedef _Float16 f16x8 __attribute__((ext_vector_type(8)));
typedef _Float16 f16x4 __attribute__((ext_vector_type(4)));
typedef float f32x4 __attribute__((ext_vector_type(4)));
typedef float f32x16 __attribute__((ext_vector_type(16)));
typedef unsigned int u32x4 __attribute__((ext_vector_type(4)));

#define MFMA16(A, Bv, Cv) __builtin_amdgcn_mfma_f32_16x16x32_f16(A, Bv, Cv, 0, 0, 0)
#define MFMA32(A, Bv, Cv) __builtin_amdgcn_mfma_f32_32x32x16_f16(A, Bv, Cv, 0, 0, 0)

#define LOG2E 1.44269504f

static __device__ __forceinline__ uint32_t pkrtz(float a, float b) {
    return __builtin_bit_cast(uint32_t, __builtin_amdgcn_cvt_pkrtz(a, b));
}

// ---------------------------------------------------------------------------
// Kernel W: all weight conversions in one launch.
//   [0, 64*512)        -> Wall (W_theta)
//   [64*512, 128*512)  -> Wall (W_phi)
//   [128*512, 384*512) -> Wall (W_g)
//   [384*512, ...)     -> Wo_h (W_o, 512*256)
// ---------------------------------------------------------------------------
__global__ __launch_bounds__(256) void cvt_all(const float* __restrict__ Wt,
                                               const float* __restrict__ Wp,
                                               const float* __restrict__ Wg,
                                               const float* __restrict__ Wo,
                                               f16* __restrict__ Wall,
                                               f16* __restrict__ Wo_h) {
    const int i = blockIdx.x * 256 + threadIdx.x;
    const int NT = CK_ * C_;          // 32768
    const int NG = CV_ * C_;          // 131072
    if (i < NT) Wall[i] = (f16)Wt[i];
    else if (i < 2 * NT) Wall[i] = (f16)Wp[i - NT];
    else if (i < 2 * NT + NG) Wall[i] = (f16)Wg[i - 2 * NT];
    else Wo_h[i - 2 * NT - NG] = (f16)Wo[i - 2 * NT - NG];
}

// ---------------------------------------------------------------------------
// Fused projection kernel (MFMA f16, fp32 accum), x staged via LDS.
//   Stage: x[b][:][l0..l0+31] fp32 -> pkrtz -> xs[64][32][8] f16 (32 KB).
//   Compute: A = Wall rows (f16, 16B/lane), B = xs frags (ds_read_b128).
//   theta written pre-scaled by log2(e) (attn softmax runs in exp2 domain).
//   phi/g maxpool2 over l via shfl_xor(1) on D cols (col = lane).
//   Outputs: theta2[b][ck>>3][l][8]  phi2[b][ck>>3][m][8]  g2[b][m>>3][v][8]
// ---------------------------------------------------------------------------
__global__ __launch_bounds__(256) void fused_proj(const f16* __restrict__ Wall,
                                                  const float* __restrict__ x,
                                                  f16* __restrict__ theta2,
                                                  f16* __restrict__ phi2,
                                                  f16* __restrict__ g2) {
    __shared__ __align__(16) f16 xs[64][32][8];  // 32 KB
    const int b    = blockIdx.y;
    const int l0   = blockIdx.x * 32;
    const int tid  = threadIdx.x;
    const int w    = tid >> 6;           // warp: och range [w*96, w*96+96)
    const int lane = tid & 63;
    const int lq   = lane & 15;
    const int g    = lane >> 4;
    const int wb   = w * 96;

    // ---- stage x tile -> LDS (f16, fragment-native) ----
    {
        const float* xb = x + (size_t)b * C_ * L_ + l0 + (tid & 31);
        const int co0 = tid >> 5;  // 0..7
#pragma unroll
        for (int i = 0; i < 8; ++i) {
            const int co = i * 8 + co0;
            float v[8];
#pragma unroll
            for (int j = 0; j < 8; ++j) v[j] = xb[(size_t)(co * 8 + j) * L_];
            u32x4 p = {pkrtz(v[0], v[1]), pkrtz(v[2], v[3]),
                       pkrtz(v[4], v[5]), pkrtz(v[6], v[7])};
            *reinterpret_cast<u32x4*>(&xs[co][tid & 31][0]) = p;
        }
    }
    __syncthreads();

    f32x4 acc[6][2] = {};
    for (int ks = 0; ks < 16; ++ks) {
        const int c0 = ks * 32;
        f16x8 Bf[2];
#pragma unroll
        for (int lt = 0; lt < 2; ++lt)
            Bf[lt] = *reinterpret_cast<const f16x8*>(&xs[ks * 4 + g][lt * 16 + lq][0]);
#pragma unroll
        for (int t = 0; t < 6; ++t) {
            f16x8 Af = *reinterpret_cast<const f16x8*>(
                Wall + (size_t)(wb + t * 16 + lq) * C_ + c0 + 8 * g);
            acc[t][0] = MFMA16(Af, Bf[0], acc[t][0]);
            acc[t][1] = MFMA16(Af, Bf[1], acc[t][1]);
        }
    }

    // Epilogue. D layout (MFMA16): row = 4g + r (och), col = lq (l).
#pragma unroll
    for (int t = 0; t < 6; ++t) {
        const int och0 = wb + t * 16;
#pragma unroll
        for (int lt = 0; lt < 2; ++lt) {
            const int l = l0 + lt * 16 + lq;
            if (och0 < 64) {
#pragma unroll
                for (int r = 0; r < 4; ++r) {
                    const int och = och0 + 4 * g + r;
                    theta2[(((size_t)b * 8 + (och >> 3)) * L_ + l) * 8 + (och & 7)] =
                        (f16)(acc[t][lt][r] * LOG2E);
                }
            } else {
#pragma unroll
                for (int r = 0; r < 4; ++r) {
                    const float pv = fmaxf(acc[t][lt][r], __shfl_xor(acc[t][lt][r], 1));
                    if (!(lane & 1)) {
                        const int m = l >> 1;
                        if (och0 < 128) {
                            const int kc = och0 - 64 + 4 * g + r;
                            phi2[(((size_t)b * 8 + (kc >> 3)) * M_ + m) * 8 + (kc & 7)] =
                                (f16)pv;
                        } else {
                            const int vc = och0 - 128 + 4 * g + r;
                            g2[(((size_t)b * 256 + (m >> 3)) * CV_ + vc) * 8 + (m & 7)] =
                                (f16)pv;
                        }
                    }
                }
            }
        }
    }
}

// ---------------------------------------------------------------------------
// Kernel B: flash attention, zero LDS / zero barriers.
//   Block = 512 thr = 8 warps = (2 q-groups of 32) x (4 v-quarters of 64).
//   512 blocks x 8 waves = 4 waves/SIMD; all warps share K through L1,
//   V L2-traffic halved vs 32-q blocks. Softmax in exp2 domain.
// ---------------------------------------------------------------------------
__global__ __launch_bounds__(512, 4) void attn_flash(const f16* __restrict__ theta2,
                                                     const f16* __restrict__ phi2,
                                                     const f16* __restrict__ g2,
                                                     f16* __restrict__ o_inT) {
    const int bid = blockIdx.x;
    const int b   = bid & 7;            // XCD-major: one batch per XCD
    const int qt  = bid >> 3;           // 64 q-tiles (of 64) per batch
    const int w   = threadIdx.x >> 6;   // 0..7
    const int qg  = w >> 2;             // 0..1
    const int vq  = w & 3;              // 0..3
    const int q0  = qt * 64 + qg * 32;
    const int vb  = vq * 64;
    const int lane = threadIdx.x & 63;
    const int lq   = lane & 31;
    const int hi   = lane >> 5;

    const f16* qbase = theta2 + (size_t)b * 8 * L_ * 8;
    f16x8 Qf[4];
#pragma unroll
    for (int f = 0; f < 4; ++f)
        Qf[f] = *reinterpret_cast<const f16x8*>(
            qbase + ((size_t)(2 * f + hi) * L_ + q0 + lq) * 8);

    f32x16 acc[2] = {};
    float m_run = -3.0e38f;
    float l_run = 0.f;

    const f16* kbase = phi2 + (size_t)b * 8 * M_ * 8;
    const f16* vbase = g2 + (size_t)b * 256 * CV_ * 8;

    for (int m0 = 0; m0 < M_; m0 += 32) {
        // ---- loads (coalesced; K identical across all 8 warps -> L1) ----
        f16x8 Kf[4];
#pragma unroll
        for (int f = 0; f < 4; ++f)
            Kf[f] = *reinterpret_cast<const f16x8*>(
                kbase + ((size_t)(2 * f + hi) * M_ + m0 + lq) * 8);
        f16x8 Vf[2][2];
#pragma unroll
        for (int ch = 0; ch < 2; ++ch)
#pragma unroll
            for (int vt = 0; vt < 2; ++vt)
                Vf[ch][vt] = *reinterpret_cast<const f16x8*>(
                    vbase + ((size_t)((m0 >> 3) + 2 * ch + hi) * CV_ +
                             vb + vt * 32 + lq) * 8);

        // ---- QK^T (scores in log2 units): S^T[m][q], col = q ----
        f32x16 S = {};
        __builtin_amdgcn_s_setprio(1);
#pragma unroll
        for (int f = 0; f < 4; ++f) S = MFMA32(Kf[f], Qf[f], S);
        __builtin_amdgcn_s_setprio(0);

        // ---- online softmax, exp2 domain (per-lane; q is lane-local) ----
        // max as a max3-fusable tree (depth 3)
        float t0 = fmaxf(fmaxf(S[0], S[1]), S[2]);
        float t1 = fmaxf(fmaxf(S[3], S[4]), S[5]);
        float t2 = fmaxf(fmaxf(S[6], S[7]), S[8]);
        float t3 = fmaxf(fmaxf(S[9], S[10]), S[11]);
        float t4 = fmaxf(fmaxf(S[12], S[13]), S[14]);
        float tm = fmaxf(fmaxf(fmaxf(t0, t1), t2),
                         fmaxf(fmaxf(t3, t4), S[15]));
        tm = fmaxf(tm, __shfl_xor(tm, 32));
        if (tm > m_run + 11.5f) {  // defer-max (11.5 log2 units ~= 8 nats)
            float sc = __builtin_amdgcn_exp2f(m_run - tm);
#pragma unroll
            for (int vt = 0; vt < 2; ++vt)
#pragma unroll
                for (int r = 0; r < 16; ++r) acc[vt][r] *= sc;
            l_run *= sc;
            m_run = tm;
        }
        float s[16];
#pragma unroll
        for (int r = 0; r < 16; ++r) s[r] = __builtin_amdgcn_exp2f(S[r] - m_run);
        // balanced sum tree
        float a0 = (s[0] + s[1]) + (s[2] + s[3]);
        float a1 = (s[4] + s[5]) + (s[6] + s[7]);
        float a2 = (s[8] + s[9]) + (s[10] + s[11]);
        float a3 = (s[12] + s[13]) + (s[14] + s[15]);
        float ls = (a0 + a1) + (a2 + a3);
        l_run += ls + __shfl_xor(ls, 32);

        // ---- P -> f16 B-fragments (cvt_pkrtz + permlane32_swap, T12) ----
        uint32_t pk[8];
#pragma unroll
        for (int i = 0; i < 8; ++i) pk[i] = pkrtz(s[2 * i], s[2 * i + 1]);
        asm volatile("v_permlane32_swap_b32 %0, %1" : "+v"(pk[0]), "+v"(pk[2]));
        asm volatile("v_permlane32_swap_b32 %0, %1" : "+v"(pk[1]), "+v"(pk[3]));
        asm volatile("v_permlane32_swap_b32 %0, %1" : "+v"(pk[4]), "+v"(pk[6]));
        asm volatile("v_permlane32_swap_b32 %0, %1" : "+v"(pk[5]), "+v"(pk[7]));
        u32x4 fr0 = {pk[0], pk[1], pk[2], pk[3]};
        u32x4 fr1 = {pk[4], pk[5], pk[6], pk[7]};
        f16x8 P0 = __builtin_bit_cast(f16x8, fr0);
        f16x8 P1 = __builtin_bit_cast(f16x8, fr1);

        // ---- PV ----
        __builtin_amdgcn_s_setprio(1);
#pragma unroll
        for (int vt = 0; vt < 2; ++vt) acc[vt] = MFMA32(Vf[0][vt], P0, acc[vt]);
#pragma unroll
        for (int vt = 0; vt < 2; ++vt) acc[vt] = MFMA32(Vf[1][vt], P1, acc[vt]);
        __builtin_amdgcn_s_setprio(0);
    }

    // ---- epilogue: normalize, store o_inT[b][q][v] ----
    const float inv = 1.f / l_run;
    f16* op = o_inT + ((size_t)b * L_ + q0 + lq) * CV_ + vb + 4 * hi;
#pragma unroll
    for (int vt = 0; vt < 2; ++vt)
#pragma unroll
        for (int rq = 0; rq < 4; ++rq) {
            f16x4 o;
#pragma unroll
            for (int j = 0; j < 4; ++j) o[j] = (f16)(acc[vt][4 * rq + j] * inv);
            *reinterpret_cast<f16x4*>(op + vt * 32 + 8 * rq) = o;
        }
}

// ---------------------------------------------------------------------------
// Kernel C: MFMA output projection + residual.
// ---------------------------------------------------------------------------
__global__ __launch_bounds__(256) void out_mfma(const f16* __restrict__ Wo_h,
                                                const f16* __restrict__ o_inT,
                                                const float* __restrict__ x,
                                                const float* __restrict__ gamma_p,
                                                float* __restrict__ out) {
    const int b    = blockIdx.z;
    const int l0   = blockIdx.x * 64;
    const int wid  = threadIdx.x >> 6;
    const int oc0  = blockIdx.y * 64 + wid * 16;
    const int lane = threadIdx.x & 63;
    const int lq   = lane & 15;
    const int g    = lane >> 4;

    f32x4 acc[4] = {{0.f, 0.f, 0.f, 0.f}, {0.f, 0.f, 0.f, 0.f},
                    {0.f, 0.f, 0.f, 0.f}, {0.f, 0.f, 0.f, 0.f}};
    const f16* ap = Wo_h + (size_t)(oc0 + lq) * CV_;
#pragma unroll
    for (int ks = 0; ks < 8; ++ks) {
        f16x8 A = *reinterpret_cast<const f16x8*>(ap + ks * 32 + 8 * g);
#pragma unroll
        for (int lt = 0; lt < 4; ++lt) {
            const f16* bp = o_inT + ((size_t)b * L_ + l0 + lt * 16 + lq) * CV_ + ks * 32 + 8 * g;
            acc[lt] = MFMA16(A, *reinterpret_cast<const f16x8*>(bp), acc[lt]);
        }
    }
    const float gamma = *gamma_p;
#pragma unroll
    for (int lt = 0; lt < 4; ++lt)
#pragma unroll
        for (int r = 0; r < 4; ++r) {
            const size_t o = ((size_t)b * C_ + oc0 + 4 * g + r) * L_ + l0 + lt * 16 + lq;
            out[o] = fmaf(gamma, acc[lt][r], x[o]);
        }
}

// ---------------------------------------------------------------------------
extern "C" void kernel_launch(void* const* d_in, const int* in_sizes, int n_in,
                              void* d_out, int out_size, void* d_ws, size_t ws_size,
                              hipStream_t stream) {
    const float* x       = (const float*)d_in[0];
    const float* W_theta = (const float*)d_in[1];
    const float* W_phi   = (const float*)d_in[2];
    const float* W_g     = (const float*)d_in[3];
    const float* W_o     = (const float*)d_in[4];
    const float* gamma   = (const float*)d_in[5];
    float* out = (float*)d_out;

    // workspace carve (f16): theta2 | phi2 | g2 | o_inT | Wo_h | Wall
    f16* theta2 = (f16*)d_ws;                          // [B][8][L][8]
    f16* phi2   = theta2 + (size_t)B_ * 8 * L_ * 8;    // [B][8][M][8]
    f16* g2     = phi2 + (size_t)B_ * 8 * M_ * 8;      // [B][256][CV][8]
    f16* o_inT  = g2 + (size_t)B_ * 256 * CV_ * 8;     // [B][L][CV]
    f16* Wo_h   = o_inT + (size_t)B_ * L_ * CV_;       // [C][CV]
    f16* Wall   = Wo_h + (size_t)C_ * CV_;             // [384][C]

    const int cvt_n = 2 * CK_ * C_ + CV_ * C_ + C_ * CV_;  // 327680
    cvt_all<<<dim3(cvt_n / 256), 256, 0, stream>>>(W_theta, W_phi, W_g, W_o, Wall, Wo_h);
    fused_proj<<<dim3(L_ / 32, B_), 256, 0, stream>>>(Wall, x, theta2, phi2, g2);
    attn_flash<<<dim3(512), 512, 0, stream>>>(theta2, phi2, g2, o_inT);
    out_mfma<<<dim3(L_ / 64, C_ / 64, B_), 256, 0, stream>>>(Wo_h, o_inT, x, gamma, out);
}